// Round 5
// baseline (188.868 us; speedup 1.0000x reference)
//
#include <hip/hip_runtime.h>

// ---------------------------------------------------------------------------
// MoE gated MLP with LoRA, top-2 of 8, T=512, H=2048, I=1024, R=16.
// Round 5: identical to round 4 except the GEMM K-loop barriers are raw
// s_barrier + lgkmcnt(0) (NOT __syncthreads), so the 2-deep register
// prefetch survives the barrier (counted vmcnt, T3/T4 pattern).
// ---------------------------------------------------------------------------

typedef short  s16x8 __attribute__((ext_vector_type(8)));
typedef float  f32x4 __attribute__((ext_vector_type(4)));
typedef unsigned short u16x8 __attribute__((ext_vector_type(8)));

__device__ __forceinline__ unsigned short f2bf(float f) {
  unsigned u = __builtin_bit_cast(unsigned, f);
  u += 0x7fffu + ((u >> 16) & 1u);          // RNE
  return (unsigned short)(u >> 16);
}

// Barrier that does NOT drain vmcnt: publishes LDS writes (lgkmcnt) and
// syncs wave arrival, but leaves global prefetch loads in flight.
#define PIPE_BARRIER() asm volatile("s_waitcnt lgkmcnt(0)\n\ts_barrier" ::: "memory")

#define GWW 2064   // gup_ws row width: 2048 gup cols + 16 LoRA-ter1 cols

// ---- workspace layout (bytes). [0, ZERO_SPAN) memset to 0 each launch ----
#define OFF_CNT    0u          // 8 int (pad 256)
#define OFF_TER2   256u        // 1024*16 f32 = 65536
#define OFF_GWS    65792u      // 1024*2064 f32 = 8454144
#define ZERO_SPAN  8519936u
#define OFF_LIST   8519936u    // 8*512 int = 16384
#define OFF_PW     8536320u    // 1024 f32 = 4096
#define OFF_WG     8540416u    // 8*2048 f32 = 65536
#define OFF_XBF    8605952u    // 512*2048 bf16 = 2097152
#define OFF_H      10703104u   // 1024*1024 bf16 = 2097152
// total 12800256 (~12.8 MB)

// ---------------------------------------------------------------------------
__global__ void k_gatecomb(const float* __restrict__ gw, const float* __restrict__ gA,
                           const float* __restrict__ gB, float* __restrict__ Wg) {
  int idx = blockIdx.x * 256 + threadIdx.x;   // 16384
  int e = idx >> 11, h = idx & 2047;
  float acc = gw[idx];
#pragma unroll
  for (int r = 0; r < 16; ++r)
    acc += 2.0f * gB[e * 16 + r] * gA[r * 2048 + h];
  Wg[idx] = acc;
}

// fp32 router (exact logits -> identical top-k to reference) + fused x->bf16.
__global__ void k_router(const float* __restrict__ x, const float* __restrict__ Wg,
                         int* __restrict__ cnt, int* __restrict__ list,
                         float* __restrict__ pw, unsigned short* __restrict__ xbf) {
  int t = blockIdx.x, tid = threadIdx.x;
  __shared__ float xs[2048];
  __shared__ float logits[8];
  for (int i = tid; i < 2048; i += 256) xs[i] = x[(size_t)t * 2048 + i];
  __syncthreads();
  {  // fused bf16 conversion of this token's row
    u16x8 o;
#pragma unroll
    for (int j = 0; j < 8; ++j) o[j] = f2bf(xs[tid * 8 + j]);
    *(u16x8*)(xbf + (size_t)t * 2048 + tid * 8) = o;
  }
  int e = tid >> 5, l = tid & 31;
  float s = 0.f;
  for (int h = l; h < 2048; h += 32) s += xs[h] * Wg[e * 2048 + h];
#pragma unroll
  for (int off = 16; off >= 1; off >>= 1) s += __shfl_down(s, off, 32);
  if (l == 0) logits[e] = s;
  __syncthreads();
  if (tid == 0) {
    float m = logits[0];
#pragma unroll
    for (int i = 1; i < 8; ++i) m = fmaxf(m, logits[i]);
    float ex[8];
#pragma unroll
    for (int i = 0; i < 8; ++i) ex[i] = __expf(logits[i] - m);
    int e1 = 0; float v1 = ex[0];
#pragma unroll
    for (int i = 1; i < 8; ++i) if (ex[i] > v1) { v1 = ex[i]; e1 = i; }
    int e2 = -1; float v2 = -1.f;
#pragma unroll
    for (int i = 0; i < 8; ++i) if (i != e1 && ex[i] > v2) { v2 = ex[i]; e2 = i; }
    float inv = 1.f / (v1 + v2);
    int p1 = 2 * t, p2 = 2 * t + 1;
    pw[p1] = v1 * inv;
    pw[p2] = v2 * inv;
    int s1 = atomicAdd(&cnt[e1], 1); list[e1 * 512 + s1] = p1;
    int s2 = atomicAdd(&cnt[e2], 1); list[e2 * 512 + s2] = p2;
  }
}

// ---------------------------------------------------------------------------
// GEMM1: gathered x rows [BM=128] x gup[e] [BN=64 cols], split-K=2 (K=1024
// each, NT=16 steps of 64). ct==32 is the LoRA-A tile (16 cols of gupA).
// 2-deep register pipeline with non-draining barriers.
__global__ __launch_bounds__(512) void k_gemm1(
    const unsigned short* __restrict__ xbf, const float* __restrict__ gup,
    const float* __restrict__ gupA,
    const int* __restrict__ cnt, const int* __restrict__ list,
    float* __restrict__ gws) {
  const int ct = blockIdx.x;                 // 0..32
  const int st = blockIdx.y >> 1, kc = blockIdx.y & 1;
  const int e  = blockIdx.z;
  const int n = cnt[e];
  if (n == 0 || st * 128 >= n) return;
  const int tid = threadIdx.x;

  __shared__ unsigned short Ap[2][128 * 64];   // [row][k] swizzled
  __shared__ unsigned short Bp[2][64 * 64];    // [col][k] swizzled

  const int k0b = kc * 1024;
  const bool lora = (ct == 32);
  const int c0 = ct * 64;

  const unsigned short *aSrc0, *aSrc1;
  int aOff0, aOff1;
  {
    int row = tid >> 3, k16 = tid & 7;
    int p = list[e * 512 + min(st * 128 + row, n - 1)];
    aSrc0 = xbf + (size_t)(p >> 1) * 2048 + k0b + k16 * 8;
    aOff0 = row * 64 + ((k16 * 8) ^ ((row & 7) << 3));
    int slot = tid + 512;
    row = slot >> 3; k16 = slot & 7;
    p = list[e * 512 + min(st * 128 + row, n - 1)];
    aSrc1 = xbf + (size_t)(p >> 1) * 2048 + k0b + k16 * 8;
    aOff1 = row * 64 + ((k16 * 8) ^ ((row & 7) << 3));
  }
  const int bcol = tid & 63, kgrp = tid >> 6;
  size_t brstr;
  const float* bSrc;
  if (!lora) {
    brstr = 2048;
    bSrc = gup + ((size_t)e * 2048 + k0b + kgrp * 8) * 2048 + c0 + bcol;
  } else {
    brstr = 1;
    bSrc = gupA + ((size_t)e * 16 + (bcol & 15)) * 2048 + k0b + kgrp * 8;
  }
  const int bOff = bcol * 64 + ((kgrp * 8) ^ ((bcol & 7) << 3));

  const int lane = tid & 63, wv = tid >> 6;
  const int lr = lane & 15, lh = lane >> 4;
  const int wr = wv >> 1, wc = wv & 1;       // 4x2 waves, 32x32 each

  uint4 a0A, a1A, a0B, a1B;
  float bA[8], bB[8];

#define G1_LOAD(SUF, T) {                                        \
    const int kk = (T) * 64;                                     \
    a0##SUF = *(const uint4*)(aSrc0 + kk);                       \
    a1##SUF = *(const uint4*)(aSrc1 + kk);                       \
    _Pragma("unroll") for (int j = 0; j < 8; ++j)                \
      b##SUF[j] = bSrc[(size_t)(kk + j) * brstr]; }

#define G1_BODY(BUF, SUF, NXT) {                                               \
    *(uint4*)&Ap[BUF][aOff0] = a0##SUF;                                        \
    *(uint4*)&Ap[BUF][aOff1] = a1##SUF;                                        \
    { u16x8 o;                                                                 \
      _Pragma("unroll") for (int j = 0; j < 8; ++j) o[j] = f2bf(b##SUF[j]);    \
      *(u16x8*)&Bp[BUF][bOff] = o; }                                           \
    PIPE_BARRIER();                                                            \
    if ((NXT) < 16) G1_LOAD(SUF, NXT);                                         \
    _Pragma("unroll") for (int ks = 0; ks < 64; ks += 32) {                    \
      int kb = ks + lh * 8;                                                    \
      s16x8 af[2], bf_[2];                                                     \
      _Pragma("unroll") for (int q = 0; q < 2; ++q) {                          \
        int ar = wr * 32 + q * 16 + lr;                                        \
        af[q] = *(const s16x8*)&Ap[BUF][ar * 64 + (kb ^ ((ar & 7) << 3))];     \
        int bc = wc * 32 + q * 16 + lr;                                        \
        bf_[q] = *(const s16x8*)&Bp[BUF][bc * 64 + (kb ^ ((bc & 7) << 3))];    \
      }                                                                        \
      _Pragma("unroll") for (int q = 0; q < 2; ++q)                            \
        _Pragma("unroll") for (int r = 0; r < 2; ++r)                          \
          acc[q][r] = __builtin_amdgcn_mfma_f32_16x16x32_bf16(af[q], bf_[r], acc[q][r], 0, 0, 0); \
    } }

  f32x4 acc[2][2] = {};
  G1_LOAD(A, 0);
  G1_LOAD(B, 1);
  for (int tt = 0; tt < 16; tt += 2) {
    G1_BODY(0, A, tt + 2);
    G1_BODY(1, B, tt + 3);
  }
#undef G1_LOAD
#undef G1_BODY

#pragma unroll
  for (int q = 0; q < 2; ++q) {
#pragma unroll
    for (int j = 0; j < 4; ++j) {
      int row = wr * 32 + q * 16 + lh * 4 + j;
      if (st * 128 + row < n) {
        int p = list[e * 512 + st * 128 + row];
        float* grow = gws + (size_t)p * GWW;
#pragma unroll
        for (int r = 0; r < 2; ++r) {
          int col = wc * 32 + r * 16 + lr;
          if (!lora) atomicAdd(grow + c0 + col, acc[q][r][j]);
          else if (col < 16) atomicAdd(grow + 2048 + col, acc[q][r][j]);
        }
      }
    }
  }
}

// h = silu(g + 2*dg) * (u + 2*du); dg/du from LoRA ters stored in gws[2048+].
__global__ __launch_bounds__(256) void k_hsilu(
    const float* __restrict__ gws, const float* __restrict__ gupB,
    const int* __restrict__ cnt, const int* __restrict__ list,
    unsigned short* __restrict__ h) {
  int slc = blockIdx.x, ic = blockIdx.y, e = blockIdx.z;
  int n = cnt[e];
  if (slc * 16 >= n) return;
  int tid = threadIdx.x;
  __shared__ int pl[16];
  __shared__ float ters[16][16];
  if (tid < 16) pl[tid] = list[e * 512 + min(slc * 16 + tid, n - 1)];
  __syncthreads();
  {
    int s = tid >> 4, r = tid & 15;
    ters[s][r] = gws[(size_t)pl[s] * GWW + 2048 + r];
  }
  __syncthreads();
  int smax = min(16, n - slc * 16);
  int i = ic * 256 + tid;
  const float4* g4 = (const float4*)(gupB + ((size_t)e * 2048 + i) * 16);
  const float4* u4 = (const float4*)(gupB + ((size_t)e * 2048 + 1024 + i) * 16);
  float g2[16], u2[16];
#pragma unroll
  for (int q = 0; q < 4; ++q) {
    float4 gv = g4[q], uv = u4[q];
    g2[q*4+0]=gv.x; g2[q*4+1]=gv.y; g2[q*4+2]=gv.z; g2[q*4+3]=gv.w;
    u2[q*4+0]=uv.x; u2[q*4+1]=uv.y; u2[q*4+2]=uv.z; u2[q*4+3]=uv.w;
  }
#pragma unroll
  for (int s = 0; s < 16; ++s) {
    int p = pl[s];
    float g = gws[(size_t)p * GWW + i];
    float u = gws[(size_t)p * GWW + 1024 + i];
    float dg = 0.f, du = 0.f;
#pragma unroll
    for (int r = 0; r < 16; ++r) { float tv = ters[s][r]; dg += tv * g2[r]; du += tv * u2[r]; }
    float gv = g + 2.f * dg, uv = u + 2.f * du;
    if (s < smax) h[(size_t)p * 1024 + i] = f2bf(gv / (1.f + __expf(-gv)) * uv);
  }
}

// GEMM2: gathered h rows x down[e], weighted atomicAdd into y. ct==32 is the
// dlA LoRA tile -> ter2. Same 2-deep pipeline; K=512 per kc, NT=8.
__global__ __launch_bounds__(512) void k_gemm2(
    const unsigned short* __restrict__ h, const float* __restrict__ down,
    const float* __restrict__ dlA,
    const int* __restrict__ cnt, const int* __restrict__ list,
    const float* __restrict__ pw, float* __restrict__ ter2,
    float* __restrict__ y) {
  const int ct = blockIdx.x;                 // 0..32
  const int st = blockIdx.y >> 1, kc = blockIdx.y & 1;
  const int e  = blockIdx.z;
  const int n = cnt[e];
  if (n == 0 || st * 128 >= n) return;
  const int tid = threadIdx.x;

  __shared__ unsigned short Ap[2][128 * 64];
  __shared__ unsigned short Bp[2][64 * 64];

  const int k0b = kc * 512;
  const bool lora = (ct == 32);
  const int c0 = ct * 64;

  const unsigned short *aSrc0, *aSrc1;
  int aOff0, aOff1;
  {
    int row = tid >> 3, k16 = tid & 7;
    int p = list[e * 512 + min(st * 128 + row, n - 1)];
    aSrc0 = h + (size_t)p * 1024 + k0b + k16 * 8;
    aOff0 = row * 64 + ((k16 * 8) ^ ((row & 7) << 3));
    int slot = tid + 512;
    row = slot >> 3; k16 = slot & 7;
    p = list[e * 512 + min(st * 128 + row, n - 1)];
    aSrc1 = h + (size_t)p * 1024 + k0b + k16 * 8;
    aOff1 = row * 64 + ((k16 * 8) ^ ((row & 7) << 3));
  }
  const int bcol = tid & 63, kgrp = tid >> 6;
  size_t brstr;
  const float* bSrc;
  if (!lora) {
    brstr = 2048;
    bSrc = down + ((size_t)e * 1024 + k0b + kgrp * 8) * 2048 + c0 + bcol;
  } else {
    brstr = 1;
    bSrc = dlA + ((size_t)e * 16 + (bcol & 15)) * 1024 + k0b + kgrp * 8;
  }
  const int bOff = bcol * 64 + ((kgrp * 8) ^ ((bcol & 7) << 3));

  const int lane = tid & 63, wv = tid >> 6;
  const int lr = lane & 15, lh = lane >> 4;
  const int wr = wv >> 1, wc = wv & 1;

  uint4 a0A, a1A, a0B, a1B;
  float bA[8], bB[8];

#define G2_LOAD(SUF, T) {                                        \
    const int kk = (T) * 64;                                     \
    a0##SUF = *(const uint4*)(aSrc0 + kk);                       \
    a1##SUF = *(const uint4*)(aSrc1 + kk);                       \
    _Pragma("unroll") for (int j = 0; j < 8; ++j)                \
      b##SUF[j] = bSrc[(size_t)(kk + j) * brstr]; }

#define G2_BODY(BUF, SUF, NXT) {                                               \
    *(uint4*)&Ap[BUF][aOff0] = a0##SUF;                                        \
    *(uint4*)&Ap[BUF][aOff1] = a1##SUF;                                        \
    { u16x8 o;                                                                 \
      _Pragma("unroll") for (int j = 0; j < 8; ++j) o[j] = f2bf(b##SUF[j]);    \
      *(u16x8*)&Bp[BUF][bOff] = o; }                                           \
    PIPE_BARRIER();                                                            \
    if ((NXT) < 8) G2_LOAD(SUF, NXT);                                          \
    _Pragma("unroll") for (int ks = 0; ks < 64; ks += 32) {                    \
      int kb = ks + lh * 8;                                                    \
      s16x8 af[2], bf_[2];                                                     \
      _Pragma("unroll") for (int q = 0; q < 2; ++q) {                          \
        int ar = wr * 32 + q * 16 + lr;                                        \
        af[q] = *(const s16x8*)&Ap[BUF][ar * 64 + (kb ^ ((ar & 7) << 3))];     \
        int bc = wc * 32 + q * 16 + lr;                                        \
        bf_[q] = *(const s16x8*)&Bp[BUF][bc * 64 + (kb ^ ((bc & 7) << 3))];    \
      }                                                                        \
      _Pragma("unroll") for (int q = 0; q < 2; ++q)                            \
        _Pragma("unroll") for (int r = 0; r < 2; ++r)                          \
          acc[q][r] = __builtin_amdgcn_mfma_f32_16x16x32_bf16(af[q], bf_[r], acc[q][r], 0, 0, 0); \
    } }

  f32x4 acc[2][2] = {};
  G2_LOAD(A, 0);
  G2_LOAD(B, 1);
  for (int tt = 0; tt < 8; tt += 2) {
    G2_BODY(0, A, tt + 2);
    G2_BODY(1, B, tt + 3);
  }
#undef G2_LOAD
#undef G2_BODY

#pragma unroll
  for (int q = 0; q < 2; ++q) {
#pragma unroll
    for (int j = 0; j < 4; ++j) {
      int row = wr * 32 + q * 16 + lh * 4 + j;
      if (st * 128 + row < n) {
        int p = list[e * 512 + st * 128 + row];
#pragma unroll
        for (int r = 0; r < 2; ++r) {
          int col = wc * 32 + r * 16 + lr;
          if (!lora) {
            atomicAdd(&y[(size_t)(p >> 1) * 2048 + c0 + col], pw[p] * acc[q][r][j]);
          } else if (col < 16) {
            atomicAdd(&ter2[p * 16 + col], acc[q][r][j]);
          }
        }
      }
    }
  }
}

// y += 2 * wt * (ter2 . dlB[e][col][:]) — ic covers 2048 cols in 8 slices.
__global__ __launch_bounds__(256) void k_dlora(
    const float* __restrict__ ter2, const float* __restrict__ dlB,
    const int* __restrict__ cnt, const int* __restrict__ list,
    const float* __restrict__ pw, float* __restrict__ y) {
  int slc = blockIdx.x, ic = blockIdx.y, e = blockIdx.z;
  int n = cnt[e];
  if (slc * 16 >= n) return;
  int tid = threadIdx.x;
  __shared__ int pl[16];
  __shared__ float wts[16];
  __shared__ float t2s[16][16];
  if (tid < 16) {
    int p = list[e * 512 + min(slc * 16 + tid, n - 1)];
    pl[tid] = p;
    wts[tid] = pw[p];
  }
  __syncthreads();
  {
    int s = tid >> 4, r = tid & 15;
    t2s[s][r] = ter2[pl[s] * 16 + r];
  }
  __syncthreads();
  int smax = min(16, n - slc * 16);
  int col = ic * 256 + tid;
  const float4* d4 = (const float4*)(dlB + ((size_t)e * 2048 + col) * 16);
  float d2[16];
#pragma unroll
  for (int q = 0; q < 4; ++q) {
    float4 v = d4[q];
    d2[q*4+0]=v.x; d2[q*4+1]=v.y; d2[q*4+2]=v.z; d2[q*4+3]=v.w;
  }
#pragma unroll
  for (int s = 0; s < 16; ++s) {
    float dd = 0.f;
#pragma unroll
    for (int r = 0; r < 16; ++r) dd += t2s[s][r] * d2[r];
    if (s < smax)
      atomicAdd(&y[(size_t)(pl[s] >> 1) * 2048 + col], 2.f * wts[s] * dd);
  }
}

// ---------------------------------------------------------------------------
extern "C" void kernel_launch(void* const* d_in, const int* in_sizes, int n_in,
                              void* d_out, int out_size, void* d_ws, size_t ws_size,
                              hipStream_t stream) {
  (void)in_sizes; (void)n_in; (void)ws_size;
  const float* x    = (const float*)d_in[0];
  const float* gw   = (const float*)d_in[1];
  const float* gA   = (const float*)d_in[2];
  const float* gB   = (const float*)d_in[3];
  const float* gup  = (const float*)d_in[4];
  const float* down = (const float*)d_in[5];
  const float* gupA = (const float*)d_in[6];
  const float* gupB = (const float*)d_in[7];
  const float* dlA  = (const float*)d_in[8];
  const float* dlB  = (const float*)d_in[9];
  float* y = (float*)d_out;

  char* w = (char*)d_ws;
  int*   cnt           = (int*)(w + OFF_CNT);
  float* ter2          = (float*)(w + OFF_TER2);
  float* gws           = (float*)(w + OFF_GWS);
  int*   list          = (int*)(w + OFF_LIST);
  float* pw            = (float*)(w + OFF_PW);
  float* Wg            = (float*)(w + OFF_WG);
  unsigned short* xbf  = (unsigned short*)(w + OFF_XBF);
  unsigned short* hbuf = (unsigned short*)(w + OFF_H);

  hipMemsetAsync(w, 0, ZERO_SPAN, stream);
  hipMemsetAsync(y, 0, (size_t)out_size * sizeof(float), stream);

  k_gatecomb<<<64, 256, 0, stream>>>(gw, gA, gB, Wg);
  k_router<<<512, 256, 0, stream>>>(x, Wg, cnt, list, pw, xbf);
  k_gemm1<<<dim3(33, 8, 8), 512, 0, stream>>>(xbf, gup, gupA, cnt, list, gws);
  k_hsilu<<<dim3(32, 4, 8), 256, 0, stream>>>(gws, gupB, cnt, list, hbuf);
  k_gemm2<<<dim3(33, 8, 8), 512, 0, stream>>>(hbuf, down, dlA, cnt, list, pw, ter2, y);
  k_dlora<<<dim3(32, 8, 8), 256, 0, stream>>>(ter2, dlB, cnt, list, pw, y);
}

// Round 6
// 132.793 us; speedup vs baseline: 1.4223x; 1.4223x over previous
//
#include <hip/hip_runtime.h>

// ---------------------------------------------------------------------------
// MoE gated MLP with LoRA, top-2 of 8, T=512, H=2048, I=1024, R=16.
// Round 6: no split-K, no fp32 gws intermediate, no epilogue atomics.
// gemm1 computes g+u cols together, fuses silu+LoRA epilogue -> bf16 h.
// gemm2 fuses down-LoRA, writes per-slot osel; k_comb combines with weights.
// ---------------------------------------------------------------------------

typedef short  s16x8 __attribute__((ext_vector_type(8)));
typedef float  f32x4 __attribute__((ext_vector_type(4)));
typedef unsigned short u16x8 __attribute__((ext_vector_type(8)));

__device__ __forceinline__ unsigned short f2bf(float f) {
  unsigned u = __builtin_bit_cast(unsigned, f);
  u += 0x7fffu + ((u >> 16) & 1u);          // RNE
  return (unsigned short)(u >> 16);
}

// Barrier that does NOT drain vmcnt.
#define PIPE_BARRIER() asm volatile("s_waitcnt lgkmcnt(0)\n\ts_barrier" ::: "memory")

// ---- workspace layout (bytes). [0, ZERO_SPAN) memset to 0 each launch ----
#define OFF_CNT    0u          // 8 int (pad 256)
#define OFF_TER1A  256u        // 512*128 f32 = 262144
#define OFF_TER2   262400u     // 1024*16 f32 = 65536
#define ZERO_SPAN  327936u
#define OFF_LIST   327936u     // 8*512 int = 16384
#define OFF_PW     344320u     // 1024 f32 = 4096
#define OFF_WG     348416u     // 8*2048 f32 = 65536
#define OFF_XBF    413952u     // 512*2048 bf16 = 2097152
#define OFF_H      2511104u    // 1024*1024 bf16 = 2097152
#define OFF_OSEL   4608256u    // 1024*2048 f32 = 8388608
// total 12996864 (~13.0 MB, round-2-proven footprint)

// ---------------------------------------------------------------------------
__global__ void k_gatecomb(const float* __restrict__ gw, const float* __restrict__ gA,
                           const float* __restrict__ gB, float* __restrict__ Wg) {
  int idx = blockIdx.x * 256 + threadIdx.x;   // 16384
  int e = idx >> 11, h = idx & 2047;
  float acc = gw[idx];
#pragma unroll
  for (int r = 0; r < 16; ++r)
    acc += 2.0f * gB[e * 16 + r] * gA[r * 2048 + h];
  Wg[idx] = acc;
}

// fp32 router (exact logits -> identical top-k to reference) + fused x->bf16.
__global__ void k_router(const float* __restrict__ x, const float* __restrict__ Wg,
                         int* __restrict__ cnt, int* __restrict__ list,
                         float* __restrict__ pw, unsigned short* __restrict__ xbf) {
  int t = blockIdx.x, tid = threadIdx.x;
  __shared__ float xs[2048];
  __shared__ float logits[8];
  for (int i = tid; i < 2048; i += 256) xs[i] = x[(size_t)t * 2048 + i];
  __syncthreads();
  {
    u16x8 o;
#pragma unroll
    for (int j = 0; j < 8; ++j) o[j] = f2bf(xs[tid * 8 + j]);
    *(u16x8*)(xbf + (size_t)t * 2048 + tid * 8) = o;
  }
  int e = tid >> 5, l = tid & 31;
  float s = 0.f;
  for (int h = l; h < 2048; h += 32) s += xs[h] * Wg[e * 2048 + h];
#pragma unroll
  for (int off = 16; off >= 1; off >>= 1) s += __shfl_down(s, off, 32);
  if (l == 0) logits[e] = s;
  __syncthreads();
  if (tid == 0) {
    float m = logits[0];
#pragma unroll
    for (int i = 1; i < 8; ++i) m = fmaxf(m, logits[i]);
    float ex[8];
#pragma unroll
    for (int i = 0; i < 8; ++i) ex[i] = __expf(logits[i] - m);
    int e1 = 0; float v1 = ex[0];
#pragma unroll
    for (int i = 1; i < 8; ++i) if (ex[i] > v1) { v1 = ex[i]; e1 = i; }
    int e2 = -1; float v2 = -1.f;
#pragma unroll
    for (int i = 0; i < 8; ++i) if (i != e1 && ex[i] > v2) { v2 = ex[i]; e2 = i; }
    float inv = 1.f / (v1 + v2);
    int p1 = 2 * t, p2 = 2 * t + 1;
    pw[p1] = v1 * inv;
    pw[p2] = v2 * inv;
    int s1 = atomicAdd(&cnt[e1], 1); list[e1 * 512 + s1] = p1;
    int s2 = atomicAdd(&cnt[e2], 1); list[e2 * 512 + s2] = p2;
  }
}

// ter1all[t][er] = x[t] . gupA_flat[er]  (er = e*16+r). Round-2-proven.
__global__ __launch_bounds__(512) void k_ter1all(
    const unsigned short* __restrict__ xbf, const float* __restrict__ gupA,
    float* __restrict__ ter1all) {
  int trow = blockIdx.x, kcc = blockIdx.y;
  int tid = threadIdx.x;
  __shared__ unsigned short Ap[2][64 * 64];
  __shared__ unsigned short Bp[2][128 * 64];
  const int k0b = kcc * 512;

  int rowA = tid >> 3, k16A = tid & 7;
  const unsigned short* aSrc = xbf + (size_t)(trow * 64 + rowA) * 2048 + k0b + k16A * 8;
  int aOff = rowA * 64 + ((k16A * 8) ^ ((rowA & 7) << 3));

  const float* bSrc[2]; int bOff[2];
#pragma unroll
  for (int s = 0; s < 2; ++s) {
    int slot = tid + s * 512;
    int er = slot >> 3, kg = slot & 7;
    bSrc[s] = gupA + (size_t)er * 2048 + k0b + kg * 8;
    bOff[s] = er * 64 + ((kg * 8) ^ ((er & 7) << 3));
  }
  int lane = tid & 63, wv = tid >> 6;
  int lr = lane & 15, lh = lane >> 4;

  uint4 apre; float4 bpre[2][2];
#define TA_ISSUE(T) { int kk = (T) * 64;                                   \
    apre = *(const uint4*)(aSrc + kk);                                     \
    _Pragma("unroll") for (int s = 0; s < 2; ++s) {                        \
      bpre[s][0] = *(const float4*)(bSrc[s] + kk);                         \
      bpre[s][1] = *(const float4*)(bSrc[s] + kk + 4); } }

  f32x4 acc[4] = {};
  TA_ISSUE(0);
  for (int t = 0; t < 8; ++t) {
    int buf = t & 1;
    *(uint4*)&Ap[buf][aOff] = apre;
#pragma unroll
    for (int s = 0; s < 2; ++s) {
      u16x8 o;
      o[0]=f2bf(bpre[s][0].x); o[1]=f2bf(bpre[s][0].y); o[2]=f2bf(bpre[s][0].z); o[3]=f2bf(bpre[s][0].w);
      o[4]=f2bf(bpre[s][1].x); o[5]=f2bf(bpre[s][1].y); o[6]=f2bf(bpre[s][1].z); o[7]=f2bf(bpre[s][1].w);
      *(u16x8*)&Bp[buf][bOff[s]] = o;
    }
    __syncthreads();
    if (t < 7) TA_ISSUE(t + 1);
#pragma unroll
    for (int ks = 0; ks < 64; ks += 32) {
      int kb = ks + lh * 8;
      int bc = wv * 16 + lr;
      s16x8 b = *(const s16x8*)&Bp[buf][bc * 64 + (kb ^ ((bc & 7) << 3))];
#pragma unroll
      for (int fr = 0; fr < 4; ++fr) {
        int ar = fr * 16 + lr;
        s16x8 a = *(const s16x8*)&Ap[buf][ar * 64 + (kb ^ ((ar & 7) << 3))];
        acc[fr] = __builtin_amdgcn_mfma_f32_16x16x32_bf16(a, b, acc[fr], 0, 0, 0);
      }
    }
    __syncthreads();
  }
#undef TA_ISSUE
#pragma unroll
  for (int fr = 0; fr < 4; ++fr)
#pragma unroll
    for (int j = 0; j < 4; ++j) {
      int tok = trow * 64 + fr * 16 + lh * 4 + j;
      atomicAdd(&ter1all[tok * 128 + wv * 16 + lr], acc[fr][j]);
    }
}

// ---------------------------------------------------------------------------
// GEMM1: gathered x rows [BM=128] x gup[e], B-tile = 64 gate cols + matching
// 64 up cols, full K=2048 (NT=32). Epilogue: silu(g+2dg)*(u+2du) -> bf16 h.
// 8 waves (4M x 2N), per wave 32 rows x (32 g-cols + 32 u-cols).
__global__ __launch_bounds__(512) void k_gemm1(
    const unsigned short* __restrict__ xbf, const float* __restrict__ gup,
    const float* __restrict__ gupB, const float* __restrict__ ter1all,
    const int* __restrict__ cnt, const int* __restrict__ list,
    unsigned short* __restrict__ h) {
  const int ct = blockIdx.x;                 // 0..15 : i-cols [ct*64, ct*64+64)
  const int st = blockIdx.y;                 // 0..3
  const int e  = blockIdx.z;
  const int n = cnt[e];
  if (st * 128 >= n) return;
  const int tid = threadIdx.x;

  __shared__ unsigned short Ap[2][128 * 64];   // [row][k] swizzled, 16 KB each
  __shared__ unsigned short Bp[2][128 * 64];   // [col][k]: cols 0..63 gate, 64..127 up

  const int c0 = ct * 64;

  const unsigned short *aSrc0, *aSrc1;
  int aOff0, aOff1;
  {
    int row = tid >> 3, k16 = tid & 7;
    int p = list[e * 512 + min(st * 128 + row, n - 1)];
    aSrc0 = xbf + (size_t)(p >> 1) * 2048 + k16 * 8;
    aOff0 = row * 64 + ((k16 * 8) ^ ((row & 7) << 3));
    int slot = tid + 512;
    row = slot >> 3; k16 = slot & 7;
    p = list[e * 512 + min(st * 128 + row, n - 1)];
    aSrc1 = xbf + (size_t)(p >> 1) * 2048 + k16 * 8;
    aOff1 = row * 64 + ((k16 * 8) ^ ((row & 7) << 3));
  }
  // B: col 0..127; global col = gate c0+col (col<64) else up 1024+c0+col-64
  const int bcol = tid & 127, kgrp = tid >> 7;   // 4 k-groups of 16
  const int gcg = (bcol < 64) ? (c0 + bcol) : (1024 + c0 + bcol - 64);
  const float* bSrc = gup + (size_t)e * 2048 * 2048 + (size_t)(kgrp * 16) * 2048 + gcg;
  const int sw = (bcol & 7) << 3;
  const int bOff0 = bcol * 64 + ((kgrp * 16) ^ sw);
  const int bOff1 = bcol * 64 + ((kgrp * 16 + 8) ^ sw);

  const int lane = tid & 63, wv = tid >> 6;
  const int lr = lane & 15, lh = lane >> 4;
  const int wr = wv >> 1, ni = wv & 1;       // 4 M-waves x 2 N-waves

  uint4 a0A, a1A, a0B, a1B;
  float bA[16], bB[16];

#define G1_LOAD(SUF, T) {                                        \
    const int kk = (T) * 64;                                     \
    a0##SUF = *(const uint4*)(aSrc0 + kk);                       \
    a1##SUF = *(const uint4*)(aSrc1 + kk);                       \
    _Pragma("unroll") for (int j = 0; j < 16; ++j)               \
      b##SUF[j] = bSrc[(size_t)(kk + j) * 2048]; }

#define G1_BODY(BUF, SUF, NXT) {                                               \
    *(uint4*)&Ap[BUF][aOff0] = a0##SUF;                                        \
    *(uint4*)&Ap[BUF][aOff1] = a1##SUF;                                        \
    { u16x8 o0, o1;                                                            \
      _Pragma("unroll") for (int j = 0; j < 8; ++j) {                          \
        o0[j] = f2bf(b##SUF[j]); o1[j] = f2bf(b##SUF[j + 8]); }                \
      *(u16x8*)&Bp[BUF][bOff0] = o0;                                           \
      *(u16x8*)&Bp[BUF][bOff1] = o1; }                                         \
    PIPE_BARRIER();                                                            \
    if ((NXT) < 32) G1_LOAD(SUF, NXT);                                         \
    _Pragma("unroll") for (int ks = 0; ks < 64; ks += 32) {                    \
      int kb = ks + lh * 8;                                                    \
      s16x8 af[2], bg[2], bu[2];                                               \
      _Pragma("unroll") for (int q = 0; q < 2; ++q) {                          \
        int ar = wr * 32 + q * 16 + lr;                                        \
        af[q] = *(const s16x8*)&Ap[BUF][ar * 64 + (kb ^ ((ar & 7) << 3))];     \
      }                                                                        \
      _Pragma("unroll") for (int r = 0; r < 2; ++r) {                          \
        int bc = ni * 32 + r * 16 + lr;                                        \
        bg[r] = *(const s16x8*)&Bp[BUF][bc * 64 + (kb ^ ((bc & 7) << 3))];     \
        bu[r] = *(const s16x8*)&Bp[BUF][(bc + 64) * 64 + (kb ^ ((bc & 7) << 3))]; \
      }                                                                        \
      _Pragma("unroll") for (int q = 0; q < 2; ++q)                            \
        _Pragma("unroll") for (int r = 0; r < 2; ++r) {                        \
          accg[q][r] = __builtin_amdgcn_mfma_f32_16x16x32_bf16(af[q], bg[r], accg[q][r], 0, 0, 0); \
          accu[q][r] = __builtin_amdgcn_mfma_f32_16x16x32_bf16(af[q], bu[r], accu[q][r], 0, 0, 0); \
        }                                                                      \
    } }

  f32x4 accg[2][2] = {}, accu[2][2] = {};
  G1_LOAD(A, 0);
  G1_LOAD(B, 1);
  for (int tt = 0; tt < 32; tt += 2) {
    G1_BODY(0, A, tt + 2);
    G1_BODY(1, B, tt + 3);
  }
#undef G1_LOAD
#undef G1_BODY

  // ---- epilogue: stage ter1 rows to LDS, fuse LoRA + silu, store bf16 h ----
  __syncthreads();
  float* tlds = (float*)&Ap[0][0];             // 128 x 16 f32 = 8 KB
  for (int idx = tid; idx < 2048; idx += 512) {
    int row = idx >> 4, c = idx & 15;
    int p = list[e * 512 + min(st * 128 + row, n - 1)];
    tlds[idx] = ter1all[(size_t)(p >> 1) * 128 + e * 16 + c];
  }
  __syncthreads();
#pragma unroll
  for (int r = 0; r < 2; ++r) {
    int gc = c0 + ni * 32 + r * 16 + lr;       // global i-col 0..1023
    const float4* g4 = (const float4*)(gupB + ((size_t)e * 2048 + gc) * 16);
    const float4* u4 = (const float4*)(gupB + ((size_t)e * 2048 + 1024 + gc) * 16);
    float gv2[16], uv2[16];
#pragma unroll
    for (int q = 0; q < 4; ++q) {
      float4 gv = g4[q], uv = u4[q];
      gv2[q*4+0]=gv.x; gv2[q*4+1]=gv.y; gv2[q*4+2]=gv.z; gv2[q*4+3]=gv.w;
      uv2[q*4+0]=uv.x; uv2[q*4+1]=uv.y; uv2[q*4+2]=uv.z; uv2[q*4+3]=uv.w;
    }
#pragma unroll
    for (int q = 0; q < 2; ++q) {
#pragma unroll
      for (int j = 0; j < 4; ++j) {
        int row = wr * 32 + q * 16 + lh * 4 + j;
        if (st * 128 + row < n) {
          int p = list[e * 512 + st * 128 + row];
          const float* tv = &tlds[row * 16];
          float dg = 0.f, du = 0.f;
#pragma unroll
          for (int rr = 0; rr < 16; ++rr) { dg += tv[rr] * gv2[rr]; du += tv[rr] * uv2[rr]; }
          float g = accg[q][r][j] + 2.f * dg;
          float u = accu[q][r][j] + 2.f * du;
          h[(size_t)p * 1024 + gc] = f2bf(g / (1.f + __expf(-g)) * u);
        }
      }
    }
  }
}

// ter2[p][r] = h[p] . dlA[e][r], grouped MFMA GEMM (BN=16), split-K=4.
// Round-2-proven.
__global__ __launch_bounds__(512) void k_ter2(
    const unsigned short* __restrict__ h, const float* __restrict__ dlA,
    const int* __restrict__ cnt, const int* __restrict__ list,
    float* __restrict__ ter2) {
  int st = blockIdx.x, kcc = blockIdx.y, e = blockIdx.z;
  int n = cnt[e];
  if (st * 128 >= n) return;
  int tid = threadIdx.x;
  __shared__ unsigned short Ap[2][128 * 64];
  __shared__ unsigned short Bp[2][16 * 64];
  const int k0b = kcc * 256;

  const unsigned short* aSrc[2]; int aOff[2];
#pragma unroll
  for (int s = 0; s < 2; ++s) {
    int slot = tid + s * 512;
    int row = slot >> 3, k16 = slot & 7;
    int p = list[e * 512 + min(st * 128 + row, n - 1)];
    aSrc[s] = h + (size_t)p * 1024 + k0b + k16 * 8;
    aOff[s] = row * 64 + ((k16 * 8) ^ ((row & 7) << 3));
  }
  const float* bSrc = nullptr; int bOff = 0;
  if (tid < 128) {
    int r = tid >> 3, kg = tid & 7;
    bSrc = dlA + ((size_t)e * 16 + r) * 1024 + k0b + kg * 8;
    bOff = r * 64 + ((kg * 8) ^ ((r & 7) << 3));
  }
  int lane = tid & 63, wv = tid >> 6;
  int lr = lane & 15, lh = lane >> 4;

  uint4 apre[2]; float4 bpre[2];
#define T2_ISSUE(T) { int kk = (T) * 64;                                   \
    _Pragma("unroll") for (int s = 0; s < 2; ++s)                          \
        apre[s] = *(const uint4*)(aSrc[s] + kk);                           \
    if (tid < 128) { bpre[0] = *(const float4*)(bSrc + kk);                \
                     bpre[1] = *(const float4*)(bSrc + kk + 4); } }

  f32x4 acc = {};
  T2_ISSUE(0);
  for (int t = 0; t < 4; ++t) {
    int buf = t & 1;
#pragma unroll
    for (int s = 0; s < 2; ++s) *(uint4*)&Ap[buf][aOff[s]] = apre[s];
    if (tid < 128) {
      u16x8 o;
      o[0]=f2bf(bpre[0].x); o[1]=f2bf(bpre[0].y); o[2]=f2bf(bpre[0].z); o[3]=f2bf(bpre[0].w);
      o[4]=f2bf(bpre[1].x); o[5]=f2bf(bpre[1].y); o[6]=f2bf(bpre[1].z); o[7]=f2bf(bpre[1].w);
      *(u16x8*)&Bp[buf][bOff] = o;
    }
    __syncthreads();
    if (t < 3) T2_ISSUE(t + 1);
#pragma unroll
    for (int ks = 0; ks < 64; ks += 32) {
      int kb = ks + lh * 8;
      s16x8 b = *(const s16x8*)&Bp[buf][lr * 64 + (kb ^ ((lr & 7) << 3))];
      int ar = wv * 16 + lr;
      s16x8 a = *(const s16x8*)&Ap[buf][ar * 64 + (kb ^ ((ar & 7) << 3))];
      acc = __builtin_amdgcn_mfma_f32_16x16x32_bf16(a, b, acc, 0, 0, 0);
    }
    __syncthreads();
  }
#undef T2_ISSUE
#pragma unroll
  for (int j = 0; j < 4; ++j) {
    int row = wv * 16 + lh * 4 + j;
    if (st * 128 + row < n) {
      int p = list[e * 512 + st * 128 + row];
      atomicAdd(&ter2[p * 16 + lr], acc[j]);
    }
  }
}

// GEMM2: gathered h rows [BM=128] x down[e] [BN=64], full K=1024 (NT=16).
// Epilogue fuses down-LoRA (2*ter2.dlB) and stores per-slot osel (no atomics).
__global__ __launch_bounds__(512) void k_gemm2(
    const unsigned short* __restrict__ h, const float* __restrict__ down,
    const float* __restrict__ dlB, const float* __restrict__ ter2,
    const int* __restrict__ cnt, const int* __restrict__ list,
    float* __restrict__ osel) {
  const int ct = blockIdx.x;                 // 0..31
  const int st = blockIdx.y;                 // 0..3
  const int e  = blockIdx.z;
  const int n = cnt[e];
  if (st * 128 >= n) return;
  const int tid = threadIdx.x;

  __shared__ unsigned short Ap[2][128 * 64];
  __shared__ unsigned short Bp[2][64 * 64];

  const int c0 = ct * 64;

  const unsigned short *aSrc0, *aSrc1;
  int aOff0, aOff1;
  {
    int row = tid >> 3, k16 = tid & 7;
    int p = list[e * 512 + min(st * 128 + row, n - 1)];
    aSrc0 = h + (size_t)p * 1024 + k16 * 8;
    aOff0 = row * 64 + ((k16 * 8) ^ ((row & 7) << 3));
    int slot = tid + 512;
    row = slot >> 3; k16 = slot & 7;
    p = list[e * 512 + min(st * 128 + row, n - 1)];
    aSrc1 = h + (size_t)p * 1024 + k16 * 8;
    aOff1 = row * 64 + ((k16 * 8) ^ ((row & 7) << 3));
  }
  const int bcol = tid & 63, kg = tid >> 6;  // 8 k-groups of 8
  const float* bSrc = down + (size_t)e * 1024 * 2048 + (size_t)(kg * 8) * 2048 + c0 + bcol;
  const int bOff = bcol * 64 + ((kg * 8) ^ ((bcol & 7) << 3));

  const int lane = tid & 63, wv = tid >> 6;
  const int lr = lane & 15, lh = lane >> 4;
  const int wr = wv >> 1, ni = wv & 1;

  uint4 a0A, a1A, a0B, a1B;
  float bA[8], bB[8];

#define G2_LOAD(SUF, T) {                                        \
    const int kk = (T) * 64;                                     \
    a0##SUF = *(const uint4*)(aSrc0 + kk);                       \
    a1##SUF = *(const uint4*)(aSrc1 + kk);                       \
    _Pragma("unroll") for (int j = 0; j < 8; ++j)                \
      b##SUF[j] = bSrc[(size_t)(kk + j) * 2048]; }

#define G2_BODY(BUF, SUF, NXT) {                                               \
    *(uint4*)&Ap[BUF][aOff0] = a0##SUF;                                        \
    *(uint4*)&Ap[BUF][aOff1] = a1##SUF;                                        \
    { u16x8 o;                                                                 \
      _Pragma("unroll") for (int j = 0; j < 8; ++j) o[j] = f2bf(b##SUF[j]);    \
      *(u16x8*)&Bp[BUF][bOff] = o; }                                           \
    PIPE_BARRIER();                                                            \
    if ((NXT) < 16) G2_LOAD(SUF, NXT);                                         \
    _Pragma("unroll") for (int ks = 0; ks < 64; ks += 32) {                    \
      int kb = ks + lh * 8;                                                    \
      s16x8 af[2], bd[2];                                                      \
      _Pragma("unroll") for (int q = 0; q < 2; ++q) {                          \
        int ar = wr * 32 + q * 16 + lr;                                        \
        af[q] = *(const s16x8*)&Ap[BUF][ar * 64 + (kb ^ ((ar & 7) << 3))];     \
      }                                                                        \
      _Pragma("unroll") for (int r = 0; r < 2; ++r) {                          \
        int bc = ni * 32 + r * 16 + lr;                                        \
        bd[r] = *(const s16x8*)&Bp[BUF][bc * 64 + (kb ^ ((bc & 7) << 3))];     \
      }                                                                        \
      _Pragma("unroll") for (int q = 0; q < 2; ++q)                            \
        _Pragma("unroll") for (int r = 0; r < 2; ++r)                          \
          acc[q][r] = __builtin_amdgcn_mfma_f32_16x16x32_bf16(af[q], bd[r], acc[q][r], 0, 0, 0); \
    } }

  f32x4 acc[2][2] = {};
  G2_LOAD(A, 0);
  G2_LOAD(B, 1);
  for (int tt = 0; tt < 16; tt += 2) {
    G2_BODY(0, A, tt + 2);
    G2_BODY(1, B, tt + 3);
  }
#undef G2_LOAD
#undef G2_BODY

  // ---- epilogue: stage ter2 to LDS, fuse down-LoRA, store osel ----
  __syncthreads();
  float* t2l = (float*)&Ap[0][0];            // 128 x 16 f32
  for (int idx = tid; idx < 2048; idx += 512) {
    int row = idx >> 4, c = idx & 15;
    int p = list[e * 512 + min(st * 128 + row, n - 1)];
    t2l[idx] = ter2[p * 16 + c];
  }
  __syncthreads();
#pragma unroll
  for (int r = 0; r < 2; ++r) {
    int yc = c0 + ni * 32 + r * 16 + lr;
    const float4* d4 = (const float4*)(dlB + ((size_t)e * 2048 + yc) * 16);
    float d2[16];
#pragma unroll
    for (int q = 0; q < 4; ++q) {
      float4 v = d4[q];
      d2[q*4+0]=v.x; d2[q*4+1]=v.y; d2[q*4+2]=v.z; d2[q*4+3]=v.w;
    }
#pragma unroll
    for (int q = 0; q < 2; ++q) {
#pragma unroll
      for (int j = 0; j < 4; ++j) {
        int row = wr * 32 + q * 16 + lh * 4 + j;
        if (st * 128 + row < n) {
          int p = list[e * 512 + st * 128 + row];
          const float* tv = &t2l[row * 16];
          float dd = 0.f;
#pragma unroll
          for (int rr = 0; rr < 16; ++rr) dd += tv[rr] * d2[rr];
          osel[(size_t)p * 2048 + yc] = acc[q][r][j] + 2.f * dd;
        }
      }
    }
  }
}

// y[t] = pw[2t]*osel[2t] + pw[2t+1]*osel[2t+1]  (overwrites all of y)
__global__ __launch_bounds__(256) void k_comb(
    const float* __restrict__ osel, const float* __restrict__ pw,
    float* __restrict__ y) {
  int i = blockIdx.x * 256 + threadIdx.x;     // float4 index, 262144 total
  int t = i >> 9;                              // 512 float4 per token row
  int c4 = i & 511;
  float w1 = pw[2 * t], w2 = pw[2 * t + 1];
  const float4* o = (const float4*)osel;
  float4 a = o[(size_t)(2 * t) * 512 + c4];
  float4 b = o[(size_t)(2 * t + 1) * 512 + c4];
  float4 rv;
  rv.x = w1 * a.x + w2 * b.x;
  rv.y = w1 * a.y + w2 * b.y;
  rv.z = w1 * a.z + w2 * b.z;
  rv.w = w1 * a.w + w2 * b.w;
  ((float4*)y)[i] = rv;
}

// ---------------------------------------------------------------------------
extern "C" void kernel_launch(void* const* d_in, const int* in_sizes, int n_in,
                              void* d_out, int out_size, void* d_ws, size_t ws_size,
                              hipStream_t stream) {
  (void)in_sizes; (void)n_in; (void)ws_size; (void)out_size;
  const float* x    = (const float*)d_in[0];
  const float* gw   = (const float*)d_in[1];
  const float* gA   = (const float*)d_in[2];
  const float* gB   = (const float*)d_in[3];
  const float* gup  = (const float*)d_in[4];
  const float* down = (const float*)d_in[5];
  const float* gupA = (const float*)d_in[6];
  const float* gupB = (const float*)d_in[7];
  const float* dlA  = (const float*)d_in[8];
  const float* dlB  = (const float*)d_in[9];
  float* y = (float*)d_out;

  char* w = (char*)d_ws;
  int*   cnt           = (int*)(w + OFF_CNT);
  float* ter1all       = (float*)(w + OFF_TER1A);
  float* ter2          = (float*)(w + OFF_TER2);
  int*   list          = (int*)(w + OFF_LIST);
  float* pw            = (float*)(w + OFF_PW);
  float* Wg            = (float*)(w + OFF_WG);
  unsigned short* xbf  = (unsigned short*)(w + OFF_XBF);
  unsigned short* hbuf = (unsigned short*)(w + OFF_H);
  float* osel          = (float*)(w + OFF_OSEL);

  hipMemsetAsync(w, 0, ZERO_SPAN, stream);

  k_gatecomb<<<64, 256, 0, stream>>>(gw, gA, gB, Wg);
  k_router<<<512, 256, 0, stream>>>(x, Wg, cnt, list, pw, xbf);
  k_ter1all<<<dim3(8, 4), 512, 0, stream>>>(xbf, gupA, ter1all);
  k_gemm1<<<dim3(16, 4, 8), 512, 0, stream>>>(xbf, gup, gupB, ter1all, cnt, list, hbuf);
  k_ter2<<<dim3(4, 4, 8), 512, 0, stream>>>(hbuf, dlA, cnt, list, ter2);
  k_gemm2<<<dim3(32, 4, 8), 512, 0, stream>>>(hbuf, down, dlB, ter2, cnt, list, osel);
  k_comb<<<1024, 256, 0, stream>>>(osel, pw, y);
}